// Round 2
// baseline (316.114 us; speedup 1.0000x reference)
//
#include <hip/hip_runtime.h>
#include <hip/hip_bf16.h>

#define BF16 __hip_bfloat16
typedef __bf16 bf16x8 __attribute__((ext_vector_type(8)));
typedef float f32x4 __attribute__((ext_vector_type(4)));

#define B_ 2
#define T_ 1024
#define D_ 1024
#define N_ 8
#define HD_ 128
#define KACT 32
#define M_ (B_*T_)      // 2048
#define NHD (N_*HD_)    // 1024

// ---------------- fp32 -> bf16 elementwise convert ----------------
__global__ __launch_bounds__(256) void f2b_kernel(const float* __restrict__ src,
                                                  BF16* __restrict__ dst, int n8) {
    int i = blockIdx.x * 256 + threadIdx.x;
    if (i >= n8) return;
    float4 a = ((const float4*)src)[i * 2];
    float4 b = ((const float4*)src)[i * 2 + 1];
    BF16 o[8];
    o[0] = __float2bfloat16(a.x); o[1] = __float2bfloat16(a.y);
    o[2] = __float2bfloat16(a.z); o[3] = __float2bfloat16(a.w);
    o[4] = __float2bfloat16(b.x); o[5] = __float2bfloat16(b.y);
    o[6] = __float2bfloat16(b.z); o[7] = __float2bfloat16(b.w);
    *(uint4*)(dst + (size_t)i * 8) = *(uint4*)o;
}

// ---------------- transpose fp32 -> bf16 (batched, 32x32 tiles) ----------------
__global__ __launch_bounds__(256) void transpose_f2b(const float* __restrict__ src,
                                                     BF16* __restrict__ dst, int R, int C) {
    __shared__ BF16 tile[32][33];
    int b = blockIdx.z;
    src += (size_t)b * R * C;
    dst += (size_t)b * R * C;
    int x = blockIdx.x * 32 + threadIdx.x;      // src col
    int ybase = blockIdx.y * 32;                // src row base
    for (int i = 0; i < 32; i += 8) {
        int y = ybase + threadIdx.y + i;
        tile[threadIdx.y + i][threadIdx.x] = __float2bfloat16(src[(size_t)y * C + x]);
    }
    __syncthreads();
    int x2 = ybase + threadIdx.x;               // dst col = src row
    int y2base = blockIdx.x * 32;               // dst row = src col
    for (int i = 0; i < 32; i += 8) {
        int y2 = y2base + threadIdx.y + i;
        dst[(size_t)y2 * R + x2] = tile[threadIdx.x][threadIdx.y + i];
    }
}

// ---------------- MFMA GEMM: C(128x128 tile) = A(M x K) * B(K x 128cols) -----
// Bt is the transposed B: Bt[n][k], ldbt. Block tile 128x128, BK=64.
#define BK 64
#define LDT 72   // BK + 8 pad (bf16 elements)

__global__ __launch_bounds__(256) void gemm_bt(
    const BF16* __restrict__ A, int lda, int aOffScale,
    const BF16* __restrict__ Bt, int ldbt, int K,
    float* __restrict__ outF, int ldc, int relu)
{
    __shared__ BF16 As[128 * LDT];
    __shared__ BF16 Bs[128 * LDT];
    int bx = blockIdx.x, by = blockIdx.y;
    const BF16* Ablk = A + (size_t)bx * 128 * lda + (size_t)by * aOffScale;
    const BF16* Bblk = Bt + (size_t)by * 128 * ldbt;
    int tid = threadIdx.x;
    int wave = tid >> 6, lane = tid & 63;
    int wm = wave >> 1, wn = wave & 1;
    int quad = lane >> 4, l16 = lane & 15;

    f32x4 acc[4][4];
#pragma unroll
    for (int i = 0; i < 4; i++)
#pragma unroll
        for (int j = 0; j < 4; j++) acc[i][j] = (f32x4)(0.f);

    for (int k0 = 0; k0 < K; k0 += BK) {
#pragma unroll
        for (int p = 0; p < 4; p++) {
            int idx = p * 256 + tid;            // 0..1023
            int row = idx >> 3;
            int kc = (idx & 7) * 8;
            *(uint4*)(&As[row * LDT + kc]) = *(const uint4*)(Ablk + (size_t)row * lda + k0 + kc);
            *(uint4*)(&Bs[row * LDT + kc]) = *(const uint4*)(Bblk + (size_t)row * ldbt + k0 + kc);
        }
        __syncthreads();
#pragma unroll
        for (int ks = 0; ks < BK; ks += 32) {
            bf16x8 af[4], bfr[4];
#pragma unroll
            for (int mt = 0; mt < 4; mt++)
                af[mt] = *(const bf16x8*)(&As[(wm * 64 + mt * 16 + l16) * LDT + ks + quad * 8]);
#pragma unroll
            for (int nt = 0; nt < 4; nt++)
                bfr[nt] = *(const bf16x8*)(&Bs[(wn * 64 + nt * 16 + l16) * LDT + ks + quad * 8]);
#pragma unroll
            for (int mt = 0; mt < 4; mt++)
#pragma unroll
                for (int nt = 0; nt < 4; nt++)
                    acc[mt][nt] = __builtin_amdgcn_mfma_f32_16x16x32_bf16(af[mt], bfr[nt], acc[mt][nt], 0, 0, 0);
        }
        __syncthreads();
    }
#pragma unroll
    for (int mt = 0; mt < 4; mt++)
#pragma unroll
        for (int nt = 0; nt < 4; nt++)
#pragma unroll
            for (int r = 0; r < 4; r++) {
                int row = bx * 128 + wm * 64 + mt * 16 + quad * 4 + r;
                int col = by * 128 + wn * 64 + nt * 16 + l16;
                float vv = acc[mt][nt][r];
                if (relu) vv = fmaxf(vv, 0.f);
                outF[(size_t)row * ldc + col] = vv;
            }
}

// same GEMM but writing bf16 (for qc = A, and hebctx path reuse)
__global__ __launch_bounds__(256) void gemm_bt_b16out(
    const BF16* __restrict__ A, int lda, int aOffScale,
    const BF16* __restrict__ Bt, int ldbt, int K,
    BF16* __restrict__ outB, int ldc)
{
    __shared__ BF16 As[128 * LDT];
    __shared__ BF16 Bs[128 * LDT];
    int bx = blockIdx.x, by = blockIdx.y;
    const BF16* Ablk = A + (size_t)bx * 128 * lda + (size_t)by * aOffScale;
    const BF16* Bblk = Bt + (size_t)by * 128 * ldbt;
    int tid = threadIdx.x;
    int wave = tid >> 6, lane = tid & 63;
    int wm = wave >> 1, wn = wave & 1;
    int quad = lane >> 4, l16 = lane & 15;

    f32x4 acc[4][4];
#pragma unroll
    for (int i = 0; i < 4; i++)
#pragma unroll
        for (int j = 0; j < 4; j++) acc[i][j] = (f32x4)(0.f);

    for (int k0 = 0; k0 < K; k0 += BK) {
#pragma unroll
        for (int p = 0; p < 4; p++) {
            int idx = p * 256 + tid;
            int row = idx >> 3;
            int kc = (idx & 7) * 8;
            *(uint4*)(&As[row * LDT + kc]) = *(const uint4*)(Ablk + (size_t)row * lda + k0 + kc);
            *(uint4*)(&Bs[row * LDT + kc]) = *(const uint4*)(Bblk + (size_t)row * ldbt + k0 + kc);
        }
        __syncthreads();
#pragma unroll
        for (int ks = 0; ks < BK; ks += 32) {
            bf16x8 af[4], bfr[4];
#pragma unroll
            for (int mt = 0; mt < 4; mt++)
                af[mt] = *(const bf16x8*)(&As[(wm * 64 + mt * 16 + l16) * LDT + ks + quad * 8]);
#pragma unroll
            for (int nt = 0; nt < 4; nt++)
                bfr[nt] = *(const bf16x8*)(&Bs[(wn * 64 + nt * 16 + l16) * LDT + ks + quad * 8]);
#pragma unroll
            for (int mt = 0; mt < 4; mt++)
#pragma unroll
                for (int nt = 0; nt < 4; nt++)
                    acc[mt][nt] = __builtin_amdgcn_mfma_f32_16x16x32_bf16(af[mt], bfr[nt], acc[mt][nt], 0, 0, 0);
        }
        __syncthreads();
    }
#pragma unroll
    for (int mt = 0; mt < 4; mt++)
#pragma unroll
        for (int nt = 0; nt < 4; nt++)
#pragma unroll
            for (int r = 0; r < 4; r++) {
                int row = bx * 128 + wm * 64 + mt * 16 + quad * 4 + r;
                int col = by * 128 + wn * 64 + nt * 16 + l16;
                outB[(size_t)row * ldc + col] = __float2bfloat16(acc[mt][nt][r]);
            }
}

// ---------------- sig: column means of q (+ strided-8 subsample) ----------------
__global__ __launch_bounds__(256) void sig_kernel(const float* __restrict__ q, float* __restrict__ sig) {
    __shared__ float red[2][256];
    int b = blockIdx.x >> 4;                 // 32 blocks: 16 per b
    int jblk = blockIdx.x & 15;
    int j = jblk * 64 + (threadIdx.x & 63);
    int ts = threadIdx.x >> 6;               // 0..3
    const float* base = q + (size_t)b * T_ * NHD + j;
    float s = 0.f, s2 = 0.f;
    for (int t = ts * 256; t < ts * 256 + 256; t++) {
        float vv = base[(size_t)t * NHD];
        s += vv;
        if ((t & 7) == 0) s2 += vv;
    }
    red[0][threadIdx.x] = s;
    red[1][threadIdx.x] = s2;
    __syncthreads();
    if (threadIdx.x < 64) {
        float a  = red[0][threadIdx.x] + red[0][threadIdx.x + 64] + red[0][threadIdx.x + 128] + red[0][threadIdx.x + 192];
        float a2 = red[1][threadIdx.x] + red[1][threadIdx.x + 64] + red[1][threadIdx.x + 128] + red[1][threadIdx.x + 192];
        sig[b * NHD + j] = a * (1.f / 1024.f) + a2 * (0.5f / 128.f);
    }
}

// ---------------- MLP layer 1: h = gelu(sig @ w1 + b1) ----------------
__global__ __launch_bounds__(256) void mlp1_kernel(const float* __restrict__ sig, const float* __restrict__ w1,
                                                   const float* __restrict__ b1, float* __restrict__ hbuf) {
    __shared__ float sg[NHD];
    int b = blockIdx.y;
    int j = blockIdx.x * 256 + threadIdx.x;  // 0..511
    for (int i = threadIdx.x; i < NHD; i += 256) sg[i] = sig[b * NHD + i];
    __syncthreads();
    float a = 0.f;
    for (int i = 0; i < NHD; i++) a += sg[i] * w1[(size_t)i * 512 + j];
    a += b1[j];
    hbuf[b * 512 + j] = 0.5f * a * (1.f + erff(a * 0.70710678118654752f));
}

// ---------------- MLP layer 2 + softplus -> mdiag ----------------
__global__ __launch_bounds__(256) void mlp2_kernel(const float* __restrict__ hbuf, const float* __restrict__ w2,
                                                   const float* __restrict__ b2, const float* __restrict__ bm,
                                                   float* __restrict__ mdiag) {
    __shared__ float hh[512];
    int b = blockIdx.y;
    int c = blockIdx.x * 256 + threadIdx.x;  // 0..1023
    for (int i = threadIdx.x; i < 512; i += 256) hh[i] = hbuf[b * 512 + i];
    __syncthreads();
    float m = 0.f;
    for (int i = 0; i < 512; i++) m += hh[i] * w2[(size_t)i * NHD + c];
    m += b2[c];
    float xm = bm[c] + 0.1f * m;
    float sp = (xm > 20.f) ? xm : log1pf(expf(xm));
    mdiag[b * NHD + c] = sp + 1e-6f;
}

// ---------------- qn = q / max(||q||,1e-12), bf16 ----------------
__global__ __launch_bounds__(256) void qn_kernel(const float* __restrict__ q, BF16* __restrict__ qn) {
    int item = blockIdx.x * 4 + (threadIdx.x >> 6);   // (row, n)
    int lane = threadIdx.x & 63;
    int row = item >> 3, n = item & 7;
    const float* base = q + (size_t)row * NHD + n * HD_;
    float2 v2 = *(const float2*)(base + lane * 2);
    float s = v2.x * v2.x + v2.y * v2.y;
#pragma unroll
    for (int m = 32; m >= 1; m >>= 1) s += __shfl_xor(s, m);
    float inv = 1.f / fmaxf(sqrtf(s), 1e-12f);
    BF16* o = qn + (size_t)row * NHD + n * HD_ + lane * 2;
    o[0] = __float2bfloat16(v2.x * inv);
    o[1] = __float2bfloat16(v2.y * inv);
}

// ---------------- sliding-window metric attention + combine ----------------
#define TT 32
#define WROWS 63    // TT + KACT - 1
#define QLD 131     // pad: stride%32==3 -> conflict-free k-row access

__global__ __launch_bounds__(256) void window_kernel(
    const float* __restrict__ q, const float* __restrict__ v,
    const float* __restrict__ mdiag, const float* __restrict__ hebctx,
    BF16* __restrict__ qc)
{
    __shared__ float qs[WROWS * QLD];
    __shared__ float vs_[WROWS * QLD];
    __shared__ float md[HD_];
    __shared__ float wl[4][KACT];

    int bxi = blockIdx.x;
    int n = bxi & 7;
    int tmp = bxi >> 3;
    int tc = tmp & 31;
    int b = tmp >> 5;
    int t0 = tc * TT;
    int tid = threadIdx.x;
    int wave = tid >> 6, lane = tid & 63;

    for (int idx = tid; idx < WROWS * HD_; idx += 256) {
        int rr = idx >> 7;
        int d = idx & 127;
        int p = t0 - (KACT - 1) + rr;
        float qv = 0.f, vv = 0.f;
        if (p >= 0) {
            size_t g = ((size_t)(b * T_ + p)) * NHD + n * HD_ + d;
            qv = q[g]; vv = v[g];
        }
        qs[rr * QLD + d] = qv;
        vs_[rr * QLD + d] = vv;
    }
    for (int d = tid; d < HD_; d += 256) md[d] = mdiag[(b * N_ + n) * HD_ + d];
    __syncthreads();

    int k = lane >> 1;       // phase A: lane = (k, d-half)
    int h = lane & 1;

    for (int i = 0; i < TT / 4; i++) {
        int tloc = i * 4 + wave;          // 0..31
        int t = t0 + tloc;
        int rowt = tloc + KACT - 1;
        const float* qrow = &qs[rowt * QLD];

        // ---- phase A: distances ----
        float ds = 0.f;
        const float* krow = &qs[(tloc + k) * QLD];
#pragma unroll 4
        for (int dd = 0; dd < 64; dd++) {
            int d = h * 64 + dd;
            float diff = qrow[d] - krow[d];
            ds += md[d] * diff * diff;
        }
        ds += __shfl_xor(ds, 1);
        float dist = sqrtf(ds + 1e-8f);
        float e = expf(-dist);
        float ssum = e;
#pragma unroll
        for (int m = 32; m >= 2; m >>= 1) ssum += __shfl_xor(ssum, m);   // sum over k (per h-half)
        float w = e / (ssum + 1e-8f);
        if (h == 0) wl[wave][k] = w;

        // ---- phase B: context (lane -> d, split 64) ----
        float c0 = 0.f, c1 = 0.f;
#pragma unroll 8
        for (int kk = 0; kk < KACT; kk++) {
            float wk = wl[wave][kk];
            const float* vrow = &vs_[(tloc + kk) * QLD];
            c0 += wk * vrow[lane];
            c1 += wk * vrow[lane + 64];
        }
        // ---- phase C: add hebbian ctx, multiply by q, store bf16 ----
        size_t gbase = ((size_t)(b * T_ + t)) * NHD + n * HD_;
        float hb0 = hebctx[gbase + lane];
        float hb1 = hebctx[gbase + lane + 64];
        float q0 = qrow[lane];
        float q1 = qrow[lane + 64];
        qc[gbase + lane]      = __float2bfloat16(q0 * (c0 + hb0));
        qc[gbase + lane + 64] = __float2bfloat16(q1 * (c1 + hb1));
    }
}

// ---------------- launch ----------------
extern "C" void kernel_launch(void* const* d_in, const int* in_sizes, int n_in,
                              void* d_out, int out_size, void* d_ws, size_t ws_size,
                              hipStream_t stream) {
    const float* x        = (const float*)d_in[0];
    const float* enc_q    = (const float*)d_in[1];
    const float* enc_v    = (const float*)d_in[2];
    const float* decoder  = (const float*)d_in[3];
    const float* hebbian  = (const float*)d_in[4];
    const float* m_w1     = (const float*)d_in[5];
    const float* m_b1     = (const float*)d_in[6];
    const float* m_w2     = (const float*)d_in[7];
    const float* m_b2     = (const float*)d_in[8];
    const float* base_metric = (const float*)d_in[9];
    float* out = (float*)d_out;

    char* ws = (char*)d_ws;
    float* q       = (float*)(ws + 0);          // 8 MB
    float* v       = (float*)(ws + 8388608);    // 8 MB
    float* hebctx  = (float*)(ws + 16777216);   // 8 MB
    BF16*  qc      = (BF16*) (ws + 25165824);   // 4 MB
    BF16*  qn      = (BF16*) (ws + 29360128);   // 4 MB
    BF16*  xb      = (BF16*) (ws + 33554432);   // 4 MB
    BF16*  encqT   = (BF16*) (ws + 37748736);   // 2 MB
    BF16*  encvT   = (BF16*) (ws + 39845888);   // 2 MB
    BF16*  decT    = (BF16*) (ws + 41943040);   // 2 MB
    BF16*  hebT    = (BF16*) (ws + 44040192);   // 256 KB
    float* sig     = (float*)(ws + 44302336);   // 8 KB
    float* mdiag   = (float*)(ws + 44310528);   // 8 KB
    float* hbuf    = (float*)(ws + 44318720);   // 4 KB

    f2b_kernel<<<dim3(1024), 256, 0, stream>>>(x, xb, M_ * D_ / 8);

    dim3 tb(32, 8);
    transpose_f2b<<<dim3(4, 32, 8),  tb, 0, stream>>>(enc_q,   encqT, 1024, 128);
    transpose_f2b<<<dim3(4, 32, 8),  tb, 0, stream>>>(enc_v,   encvT, 1024, 128);
    transpose_f2b<<<dim3(32, 32, 1), tb, 0, stream>>>(decoder, decT,  1024, 1024);
    transpose_f2b<<<dim3(4, 4, 8),   tb, 0, stream>>>(hebbian, hebT,  128, 128);

    // q = relu(x @ enc_q), v = relu(x @ enc_v)   (fp32 out)
    gemm_bt<<<dim3(16, 8), 256, 0, stream>>>(xb, 1024, 0, encqT, 1024, 1024, q, 1024, 1);
    gemm_bt<<<dim3(16, 8), 256, 0, stream>>>(xb, 1024, 0, encvT, 1024, 1024, v, 1024, 1);

    sig_kernel<<<dim3(32), 256, 0, stream>>>(q, sig);
    mlp1_kernel<<<dim3(2, 2), 256, 0, stream>>>(sig, m_w1, m_b1, hbuf);
    mlp2_kernel<<<dim3(4, 2), 256, 0, stream>>>(hbuf, m_w2, m_b2, base_metric, mdiag);

    qn_kernel<<<dim3(4096), 256, 0, stream>>>(q, qn);
    // hebctx = qn @ hebbian  (per n)
    gemm_bt<<<dim3(16, 8), 256, 0, stream>>>(qn, 1024, 128, hebT, 128, 128, hebctx, 1024, 0);

    window_kernel<<<dim3(512), 256, 0, stream>>>(q, v, mdiag, hebctx, qc);

    // out = qc @ decoder  (fp32 out)
    gemm_bt<<<dim3(16, 8), 256, 0, stream>>>(qc, 1024, 0, decT, 1024, 1024, out, 1024, 0);
}

// Round 4
// 200.144 us; speedup vs baseline: 1.5794x; 1.5794x over previous
//
#include <hip/hip_runtime.h>
#include <hip/hip_bf16.h>

#define BF16 __hip_bfloat16
typedef __bf16 bf16x8 __attribute__((ext_vector_type(8)));
typedef float f32x4 __attribute__((ext_vector_type(4)));

#define B_ 2
#define T_ 1024
#define D_ 1024
#define N_ 8
#define HD_ 128
#define KACT 32
#define M_ (B_*T_)      // 2048
#define NHD (N_*HD_)    // 1024
#define QVLD 2048       // row stride of merged q|v fp32 buffer

// ---------------- fp32 -> bf16 elementwise convert ----------------
__global__ __launch_bounds__(256) void f2b_kernel(const float* __restrict__ src,
                                                  BF16* __restrict__ dst, int n8) {
    int i = blockIdx.x * 256 + threadIdx.x;
    if (i >= n8) return;
    float4 a = ((const float4*)src)[i * 2];
    float4 b = ((const float4*)src)[i * 2 + 1];
    BF16 o[8];
    o[0] = __float2bfloat16(a.x); o[1] = __float2bfloat16(a.y);
    o[2] = __float2bfloat16(a.z); o[3] = __float2bfloat16(a.w);
    o[4] = __float2bfloat16(b.x); o[5] = __float2bfloat16(b.y);
    o[6] = __float2bfloat16(b.z); o[7] = __float2bfloat16(b.w);
    *(uint4*)(dst + (size_t)i * 8) = *(uint4*)o;
}

// ---------------- transpose fp32 -> bf16 (batched, 32x32 tiles) ----------------
__global__ __launch_bounds__(256) void transpose_f2b(const float* __restrict__ src,
                                                     BF16* __restrict__ dst, int R, int C) {
    __shared__ BF16 tile[32][33];
    int b = blockIdx.z;
    src += (size_t)b * R * C;
    dst += (size_t)b * R * C;
    int x = blockIdx.x * 32 + threadIdx.x;      // src col
    int ybase = blockIdx.y * 32;                // src row base
    for (int i = 0; i < 32; i += 8) {
        int y = ybase + threadIdx.y + i;
        tile[threadIdx.y + i][threadIdx.x] = __float2bfloat16(src[(size_t)y * C + x]);
    }
    __syncthreads();
    int x2 = ybase + threadIdx.x;               // dst col = src row
    int y2base = blockIdx.x * 32;               // dst row = src col
    for (int i = 0; i < 32; i += 8) {
        int y2 = y2base + threadIdx.y + i;
        dst[(size_t)y2 * R + x2] = tile[threadIdx.x][threadIdx.y + i];
    }
}

// ---------------- MFMA GEMM: C(128x128 tile) = A(M x K) * B(K x 128cols) -----
#define BK 64
#define LDT 72   // BK + 8 pad (bf16 elements)

__global__ __launch_bounds__(256) void gemm_bt(
    const BF16* __restrict__ A, int lda, int aOffScale,
    const BF16* __restrict__ Bt, int ldbt, int K,
    float* __restrict__ outF, int ldc, int relu)
{
    __shared__ BF16 As[128 * LDT];
    __shared__ BF16 Bs[128 * LDT];
    int bx = blockIdx.x, by = blockIdx.y;
    const BF16* Ablk = A + (size_t)bx * 128 * lda + (size_t)by * aOffScale;
    const BF16* Bblk = Bt + (size_t)by * 128 * ldbt;
    int tid = threadIdx.x;
    int wave = tid >> 6, lane = tid & 63;
    int wm = wave >> 1, wn = wave & 1;
    int quad = lane >> 4, l16 = lane & 15;

    f32x4 acc[4][4];
#pragma unroll
    for (int i = 0; i < 4; i++)
#pragma unroll
        for (int j = 0; j < 4; j++) acc[i][j] = (f32x4)(0.f);

    for (int k0 = 0; k0 < K; k0 += BK) {
#pragma unroll
        for (int p = 0; p < 4; p++) {
            int idx = p * 256 + tid;            // 0..1023
            int row = idx >> 3;
            int kc = (idx & 7) * 8;
            *(uint4*)(&As[row * LDT + kc]) = *(const uint4*)(Ablk + (size_t)row * lda + k0 + kc);
            *(uint4*)(&Bs[row * LDT + kc]) = *(const uint4*)(Bblk + (size_t)row * ldbt + k0 + kc);
        }
        __syncthreads();
#pragma unroll
        for (int ks = 0; ks < BK; ks += 32) {
            bf16x8 af[4], bfr[4];
#pragma unroll
            for (int mt = 0; mt < 4; mt++)
                af[mt] = *(const bf16x8*)(&As[(wm * 64 + mt * 16 + l16) * LDT + ks + quad * 8]);
#pragma unroll
            for (int nt = 0; nt < 4; nt++)
                bfr[nt] = *(const bf16x8*)(&Bs[(wn * 64 + nt * 16 + l16) * LDT + ks + quad * 8]);
#pragma unroll
            for (int mt = 0; mt < 4; mt++)
#pragma unroll
                for (int nt = 0; nt < 4; nt++)
                    acc[mt][nt] = __builtin_amdgcn_mfma_f32_16x16x32_bf16(af[mt], bfr[nt], acc[mt][nt], 0, 0, 0);
        }
        __syncthreads();
    }
#pragma unroll
    for (int mt = 0; mt < 4; mt++)
#pragma unroll
        for (int nt = 0; nt < 4; nt++)
#pragma unroll
            for (int r = 0; r < 4; r++) {
                int row = bx * 128 + wm * 64 + mt * 16 + quad * 4 + r;
                int col = by * 128 + wn * 64 + nt * 16 + l16;
                float vv = acc[mt][nt][r];
                if (relu) vv = fmaxf(vv, 0.f);
                outF[(size_t)row * ldc + col] = vv;
            }
}

// ---------------- sig: weighted column sum of q, split-T atomic ----------------
// sig[b,j] = sum_t w_t * q[b,t,j],  w_t = 1/1024 + (t%8==0)*0.5/128
__global__ __launch_bounds__(256) void sig_partial(const float* __restrict__ q, float* __restrict__ sigacc) {
    __shared__ float red[4][64];
    int tch = blockIdx.x;     // 0..7  (128 t each)
    int jch = blockIdx.y;     // 0..15 (64 j each)
    int b   = blockIdx.z;
    int jl = threadIdx.x & 63;
    int ts = threadIdx.x >> 6;
    int j = jch * 64 + jl;
    int t0 = tch * 128 + ts * 32;
    const float* base = q + ((size_t)(b * T_) + t0) * QVLD + j;
    float s = 0.f;
#pragma unroll 8
    for (int i = 0; i < 32; i++) {
        int t = t0 + i;
        float w = 0.0009765625f + (((t & 7) == 0) ? 0.00390625f : 0.f);
        s += w * base[(size_t)i * QVLD];
    }
    red[ts][jl] = s;
    __syncthreads();
    if (threadIdx.x < 64) {
        float a = red[0][jl] + red[1][jl] + red[2][jl] + red[3][jl];
        atomicAdd(&sigacc[b * NHD + j], a);
    }
}

// ---------------- MLP layer 1 partial: h_pre += sig-chunk @ w1-chunk ----------------
__global__ __launch_bounds__(256) void mlp1_partial(const float* __restrict__ sigacc, const float* __restrict__ w1,
                                                    float* __restrict__ h_pre) {
    __shared__ float sg[64];
    int jch = blockIdx.x;   // 0..1   (256 j each)
    int ich = blockIdx.y;   // 0..15  (64 i each)
    int b   = blockIdx.z;
    int j = jch * 256 + threadIdx.x;
    if (threadIdx.x < 64) sg[threadIdx.x] = sigacc[b * NHD + ich * 64 + threadIdx.x];
    __syncthreads();
    float a = 0.f;
    const float* wp = w1 + (size_t)(ich * 64) * 512 + j;
#pragma unroll 8
    for (int i = 0; i < 64; i++) a += sg[i] * wp[(size_t)i * 512];
    atomicAdd(&h_pre[b * 512 + j], a);
}

// ---------------- MLP layer 2 partial: m_acc += gelu(h_pre+b1)-chunk @ w2-chunk ----
__global__ __launch_bounds__(256) void mlp2_partial(const float* __restrict__ h_pre, const float* __restrict__ b1,
                                                    const float* __restrict__ w2, float* __restrict__ m_acc) {
    __shared__ float hh[64];
    int cch = blockIdx.x;   // 0..3  (256 c each)
    int ich = blockIdx.y;   // 0..7  (64 i each)
    int b   = blockIdx.z;
    int c = cch * 256 + threadIdx.x;
    if (threadIdx.x < 64) {
        int i = ich * 64 + threadIdx.x;
        float a = h_pre[b * 512 + i] + b1[i];
        hh[threadIdx.x] = 0.5f * a * (1.f + erff(a * 0.70710678118654752f));
    }
    __syncthreads();
    float m = 0.f;
    const float* wp = w2 + (size_t)(ich * 64) * NHD + c;
#pragma unroll 8
    for (int i = 0; i < 64; i++) m += hh[i] * wp[(size_t)i * NHD];
    atomicAdd(&m_acc[b * NHD + c], m);
}

// ---------------- mdiag = softplus(bm + 0.1*(m_acc + b2)) + 1e-6 ----------------
__global__ __launch_bounds__(256) void mdiag_final(const float* __restrict__ m_acc, const float* __restrict__ b2,
                                                   const float* __restrict__ bm, float* __restrict__ mdiag) {
    int idx = blockIdx.x * 256 + threadIdx.x;  // 0..2047
    int c = idx & (NHD - 1);
    float xm = bm[c] + 0.1f * (m_acc[idx] + b2[c]);
    float sp = (xm > 20.f) ? xm : log1pf(expf(xm));
    mdiag[idx] = sp + 1e-6f;
}

// ---------------- qn = q / max(||q||,1e-12), bf16 ----------------
__global__ __launch_bounds__(256) void qn_kernel(const float* __restrict__ q, BF16* __restrict__ qn) {
    int item = blockIdx.x * 4 + (threadIdx.x >> 6);   // (row, n)
    int lane = threadIdx.x & 63;
    int row = item >> 3, n = item & 7;
    const float* base = q + (size_t)row * QVLD + n * HD_;
    float2 v2 = *(const float2*)(base + lane * 2);
    float s = v2.x * v2.x + v2.y * v2.y;
#pragma unroll
    for (int m = 32; m >= 1; m >>= 1) s += __shfl_xor(s, m);
    float inv = 1.f / fmaxf(sqrtf(s), 1e-12f);
    BF16* o = qn + (size_t)row * NHD + n * HD_ + lane * 2;
    o[0] = __float2bfloat16(v2.x * inv);
    o[1] = __float2bfloat16(v2.y * inv);
}

// ---------------- sliding-window metric attention + combine ----------------
#define TT 32
#define WROWS 63    // TT + KACT - 1
#define QLD 131     // pad: stride%32==3 -> conflict-free k-row access

__global__ __launch_bounds__(256) void window_kernel(
    const float* __restrict__ q, const float* __restrict__ v,
    const float* __restrict__ mdiag, const float* __restrict__ hebctx,
    BF16* __restrict__ qc)
{
    __shared__ float qs[WROWS * QLD];
    __shared__ float vs_[WROWS * QLD];
    __shared__ float md[HD_];
    __shared__ float wl[4][KACT];

    int bxi = blockIdx.x;
    int n = bxi & 7;
    int tmp = bxi >> 3;
    int tc = tmp & 31;
    int b = tmp >> 5;
    int t0 = tc * TT;
    int tid = threadIdx.x;
    int wave = tid >> 6, lane = tid & 63;

    for (int idx = tid; idx < WROWS * HD_; idx += 256) {
        int rr = idx >> 7;
        int d = idx & 127;
        int p = t0 - (KACT - 1) + rr;
        float qv = 0.f, vv = 0.f;
        if (p >= 0) {
            size_t g = ((size_t)(b * T_ + p)) * QVLD + n * HD_ + d;
            qv = q[g]; vv = v[g];
        }
        qs[rr * QLD + d] = qv;
        vs_[rr * QLD + d] = vv;
    }
    for (int d = tid; d < HD_; d += 256) md[d] = mdiag[(b * N_ + n) * HD_ + d];
    __syncthreads();

    int k = lane >> 1;       // phase A: lane = (k, d-half)
    int h = lane & 1;

    for (int i = 0; i < TT / 4; i++) {
        int tloc = i * 4 + wave;          // 0..31
        int t = t0 + tloc;
        int rowt = tloc + KACT - 1;
        const float* qrow = &qs[rowt * QLD];

        // ---- phase A: distances ----
        float ds = 0.f;
        const float* krow = &qs[(tloc + k) * QLD];
#pragma unroll 4
        for (int dd = 0; dd < 64; dd++) {
            int d = h * 64 + dd;
            float diff = qrow[d] - krow[d];
            ds += md[d] * diff * diff;
        }
        ds += __shfl_xor(ds, 1);
        float dist = sqrtf(ds + 1e-8f);
        float e = expf(-dist);
        float ssum = e;
#pragma unroll
        for (int m = 32; m >= 2; m >>= 1) ssum += __shfl_xor(ssum, m);   // sum over k (per h-half)
        float w = e / (ssum + 1e-8f);
        if (h == 0) wl[wave][k] = w;

        // ---- phase B: context (lane -> d, split 64) ----
        float c0 = 0.f, c1 = 0.f;
#pragma unroll 8
        for (int kk = 0; kk < KACT; kk++) {
            float wk = wl[wave][kk];
            const float* vrow = &vs_[(tloc + kk) * QLD];
            c0 += wk * vrow[lane];
            c1 += wk * vrow[lane + 64];
        }
        // ---- phase C: add hebbian ctx, multiply by q, store bf16 ----
        size_t gbase = ((size_t)(b * T_ + t)) * NHD + n * HD_;
        float hb0 = hebctx[gbase + lane];
        float hb1 = hebctx[gbase + lane + 64];
        float q0 = qrow[lane];
        float q1 = qrow[lane + 64];
        qc[gbase + lane]      = __float2bfloat16(q0 * (c0 + hb0));
        qc[gbase + lane + 64] = __float2bfloat16(q1 * (c1 + hb1));
    }
}

// ---------------- launch ----------------
extern "C" void kernel_launch(void* const* d_in, const int* in_sizes, int n_in,
                              void* d_out, int out_size, void* d_ws, size_t ws_size,
                              hipStream_t stream) {
    const float* x        = (const float*)d_in[0];
    const float* enc_q    = (const float*)d_in[1];
    const float* enc_v    = (const float*)d_in[2];
    const float* decoder  = (const float*)d_in[3];
    const float* hebbian  = (const float*)d_in[4];
    const float* m_w1     = (const float*)d_in[5];
    const float* m_b1     = (const float*)d_in[6];
    const float* m_w2     = (const float*)d_in[7];
    const float* m_b2     = (const float*)d_in[8];
    const float* base_metric = (const float*)d_in[9];
    float* out = (float*)d_out;

    char* ws = (char*)d_ws;
    float* qv      = (float*)(ws + 0);          // 16 MB, q|v merged, ld 2048
    float* hebctx  = (float*)(ws + 16777216);   // 8 MB
    BF16*  qc      = (BF16*) (ws + 25165824);   // 4 MB
    BF16*  qn      = (BF16*) (ws + 29360128);   // 4 MB
    BF16*  xb      = (BF16*) (ws + 33554432);   // 4 MB
    BF16*  encT    = (BF16*) (ws + 37748736);   // 4 MB, encqT then encvT
    BF16*  decT    = (BF16*) (ws + 41943040);   // 2 MB
    BF16*  hebT    = (BF16*) (ws + 44040192);   // 256 KB
    float* sigacc  = (float*)(ws + 44302336);   // 8 KB, zeroed
    float* h_pre   = (float*)(ws + 44310528);   // 4 KB, zeroed
    float* m_acc   = (float*)(ws + 44314624);   // 8 KB, zeroed
    float* mdiag   = (float*)(ws + 44322816);   // 8 KB

    float* q = qv;            // row stride QVLD
    float* v = qv + 1024;     // row stride QVLD

    (void)hipMemsetAsync(sigacc, 0, (2048 + 1024 + 2048) * sizeof(float), stream);

    f2b_kernel<<<dim3(1024), 256, 0, stream>>>(x, xb, M_ * D_ / 8);

    dim3 tb(32, 8);
    transpose_f2b<<<dim3(4, 32, 8),  tb, 0, stream>>>(enc_q,   encT,               1024, 128);
    transpose_f2b<<<dim3(4, 32, 8),  tb, 0, stream>>>(enc_v,   encT + 1024 * 1024, 1024, 128);
    transpose_f2b<<<dim3(32, 32, 1), tb, 0, stream>>>(decoder, decT,  1024, 1024);
    transpose_f2b<<<dim3(4, 4, 8),   tb, 0, stream>>>(hebbian, hebT,  128, 128);

    // qv = relu(x @ [enc_q | enc_v])  -- one full-machine launch, 256 blocks
    gemm_bt<<<dim3(16, 16), 256, 0, stream>>>(xb, 1024, 0, encT, 1024, 1024, qv, QVLD, 1);

    sig_partial<<<dim3(8, 16, 2), 256, 0, stream>>>(q, sigacc);
    mlp1_partial<<<dim3(2, 16, 2), 256, 0, stream>>>(sigacc, m_w1, h_pre);
    mlp2_partial<<<dim3(4, 8, 2), 256, 0, stream>>>(h_pre, m_b1, m_w2, m_acc);
    mdiag_final<<<dim3(8), 256, 0, stream>>>(m_acc, m_b2, base_metric, mdiag);

    qn_kernel<<<dim3(4096), 256, 0, stream>>>(q, qn);
    // hebctx = qn @ hebbian  (per n)
    gemm_bt<<<dim3(16, 8), 256, 0, stream>>>(qn, 1024, 128, hebT, 128, 128, hebctx, 1024, 0);

    window_kernel<<<dim3(512), 256, 0, stream>>>(q, v, mdiag, hebctx, qc);

    // out = qc @ decoder  (fp32 out)
    gemm_bt<<<dim3(16, 8), 256, 0, stream>>>(qc, 1024, 0, decT, 1024, 1024, out, 1024, 0);
}